// Round 1
// 197.370 us; speedup vs baseline: 1.0909x; 1.0909x over previous
//
#include <hip/hip_runtime.h>
#include <stdint.h>

#define TOKENS 16384
#define DDIM   1024
#define NEXP   64
#define NCOL   128              // 64 gate + 64 noise cols
#define MT     64               // tokens per GEMM block
#define KB     16               // k-tile (16 -> 16.6 KB LDS -> 8 blocks/CU)
#define KSPLIT 8
#define KCH    (DDIM / KSPLIT)  // 128 k per block
#define NTT    (TOKENS / MT)    // 256 token tiles

// -------- device-global scratch --------
__device__ float g_part[KSPLIT][TOKENS][NCOL];  // 67 MB split-K partials
__device__ float g_ps[NEXP];                    // sum of clean router probs per expert
__device__ float g_cnt[NEXP];                   // top-2 counts per expert
__device__ float g_spa[1];                      // sum of softplus

// ---------------- JAX threefry2x32 (20 rounds) ----------------
struct U2 { uint32_t a, b; };

__host__ __device__ constexpr U2 tf2x32(uint32_t k0, uint32_t k1,
                                        uint32_t x0, uint32_t x1) {
  uint32_t ks[3] = {k0, k1, k0 ^ k1 ^ 0x1BD11BDAu};
  const uint32_t rot[2][4] = {{13u, 15u, 26u, 6u}, {17u, 29u, 16u, 24u}};
  x0 += ks[0]; x1 += ks[1];
  for (int d = 0; d < 5; ++d) {
    for (int j = 0; j < 4; ++j) {
      uint32_t r = rot[d & 1][j];
      x0 += x1;
      x1 = (x1 << r) | (x1 >> (32u - r));
      x1 ^= x0;
    }
    x0 += ks[(d + 1) % 3];
    x1 += ks[(d + 2) % 3] + (uint32_t)(d + 1);
  }
  return U2{x0, x1};
}

// JAX >=0.5 partitionable threefry: bits[i] = xor-fold(tf(key, (0, i)))
__device__ inline uint32_t noise_bits(uint32_t i) {
  constexpr U2 NK = tf2x32(0u, 0u, 0u, 12345u);   // fold_in(key(0), 12345)
  U2 o = tf2x32(NK.a, NK.b, 0u, i);
  return o.a ^ o.b;
}

// XLA ErfInv32 (Giles polynomial)
__device__ inline float xla_erfinv(float x) {
  float w = -log1pf(-x * x);
  float p;
  if (w < 5.0f) {
    w = w - 2.5f;
    p = 2.81022636e-08f;
    p = 3.43273939e-07f + p * w;
    p = -3.5233877e-06f + p * w;
    p = -4.39150654e-06f + p * w;
    p = 0.00021858087f + p * w;
    p = -0.00125372503f + p * w;
    p = -0.00417768164f + p * w;
    p = 0.246640727f + p * w;
    p = 1.50140941f + p * w;
  } else {
    w = sqrtf(w) - 3.0f;
    p = -0.000200214257f;
    p = 0.000100950558f + p * w;
    p = 0.00134934322f + p * w;
    p = -0.00367342844f + p * w;
    p = 0.00573950773f + p * w;
    p = -0.0076224613f + p * w;
    p = 0.00943887047f + p * w;
    p = 1.00167406f + p * w;
    p = 2.83297682f + p * w;
  }
  return p * x;
}

__device__ inline float noise_normal(uint32_t i) {
  uint32_t bits = noise_bits(i);
  float f = __uint_as_float((bits >> 9) | 0x3f800000u) - 1.0f;  // [0,1)
  float u = f * 2.0f + (-0.99999994f);
  u = fmaxf(u, -0.99999994f);
  return 1.41421356237f * xla_erfinv(u);
}

__device__ inline float softplus_ref(float x) {
  return fmaxf(x, 0.0f) + log1pf(expf(-fabsf(x)));
}

// ---------------- wave(64) primitives ----------------
__device__ inline float wave_max64(float v) {
  #pragma unroll
  for (int off = 32; off; off >>= 1) v = fmaxf(v, __shfl_xor(v, off, 64));
  return v;
}
__device__ inline float wave_sum64(float v) {
  #pragma unroll
  for (int off = 32; off; off >>= 1) v += __shfl_xor(v, off, 64);
  return v;
}
__device__ inline void wave_argmax64(float v, int idx, float& mv, int& mi) {
  float bv = v; int bi = idx;
  #pragma unroll
  for (int off = 32; off; off >>= 1) {
    float ov = __shfl_xor(bv, off, 64);
    int   oi = __shfl_xor(bi, off, 64);
    if (ov > bv || (ov == bv && oi < bi)) { bv = ov; bi = oi; }
  }
  mv = bv; mi = bi;
}

// interleaved column mapping: stride 12 words per 8-col group -> 2-way banks (free)
__device__ __forceinline__ int wcol(int c) { return c + ((c >> 3) << 2); }

// ---------------- K1: split-K GEMM, 8x8 micro-tile, 128 threads ----------------
// block = 64 tokens x 128 cols x 128 k; grid = (256 token-tiles, 8 k-splits)
// LDS 16.6 KB -> 8 blocks/CU; VGPR budget 128 -> 4 waves/SIMD
__global__ __launch_bounds__(128, 4)
void NoisyTopKRouter_57621281243491_kernel(
    const float* __restrict__ x, const float* __restrict__ wg,
    const float* __restrict__ wn) {
  // zero loss accumulators (kernel-boundary ordering vs epilogue)
  if (blockIdx.x == 0 && blockIdx.y == 0) {
    if (threadIdx.x < NEXP) { g_ps[threadIdx.x] = 0.0f; g_cnt[threadIdx.x] = 0.0f; }
    if (threadIdx.x == NEXP) g_spa[0] = 0.0f;
  }

  __shared__ float xs[KB][MT + 4];   // x^T tile: xs[k][token]  [16][68] = 4.35 KB
  __shared__ float wsd[KB][192];     // W^T tile: wsd[k][wcol(col)]     = 12.3 KB

  const int tid = threadIdx.x;
  const int tx = tid & 15;    // col group: cols tx*8..+7
  const int ty = tid >> 4;    // token group: tokens ty*8..+7 (0..7)
  const int tok0 = blockIdx.x * MT;
  const int k0   = blockIdx.y * KCH;

  const int stok = tid >> 1;         // 0..63: x staging token
  const int skb  = (tid & 1) * 8;    // x staging k offset (0 or 8)
  const int wcl  = tid;              // 0..127: W staging col
  const float* wrow = (wcl < NEXP) ? (wg + (size_t)wcl * DDIM)
                                   : (wn + (size_t)(wcl - NEXP) * DDIM);
  const int wc = wcol(wcl);

  float acc[8][8] = {};

  for (int kt = 0; kt < KCH / KB; ++kt) {   // 8 k-tiles of 16
    const int kk0 = k0 + kt * KB;

    float4 xv[2], wv[4];
    #pragma unroll
    for (int it = 0; it < 2; ++it)
      xv[it] = *(const float4*)&x[(size_t)(tok0 + stok) * DDIM + kk0 + skb + it * 4];
    #pragma unroll
    for (int it = 0; it < 4; ++it)
      wv[it] = *(const float4*)&wrow[kk0 + it * 4];

    #pragma unroll
    for (int it = 0; it < 2; ++it) {
      const int kb = skb + it * 4;
      xs[kb + 0][stok] = xv[it].x; xs[kb + 1][stok] = xv[it].y;
      xs[kb + 2][stok] = xv[it].z; xs[kb + 3][stok] = xv[it].w;
    }
    #pragma unroll
    for (int it = 0; it < 4; ++it) {
      const int kb = it * 4;
      wsd[kb + 0][wc] = wv[it].x; wsd[kb + 1][wc] = wv[it].y;
      wsd[kb + 2][wc] = wv[it].z; wsd[kb + 3][wc] = wv[it].w;
    }
    __syncthreads();

    #pragma unroll
    for (int kk = 0; kk < KB; ++kk) {
      const float4 a0 = *(const float4*)&xs[kk][ty * 8];        // 16-lane broadcast
      const float4 a1 = *(const float4*)&xs[kk][ty * 8 + 4];
      const float4 b0 = *(const float4*)&wsd[kk][tx * 12];      // wcol(tx*8): 2-way banks
      const float4 b1 = *(const float4*)&wsd[kk][tx * 12 + 4];
      const float av[8] = {a0.x, a0.y, a0.z, a0.w, a1.x, a1.y, a1.z, a1.w};
      const float bv[8] = {b0.x, b0.y, b0.z, b0.w, b1.x, b1.y, b1.z, b1.w};
      #pragma unroll
      for (int i = 0; i < 8; ++i)
        #pragma unroll
        for (int j = 0; j < 8; ++j)
          acc[i][j] += av[i] * bv[j];
    }
    __syncthreads();
  }

  // write split-K partials (coalesced float4, plain column layout)
  float* dst = &g_part[blockIdx.y][0][0];
  #pragma unroll
  for (int i = 0; i < 8; ++i) {
    const size_t t = (size_t)(tok0 + ty * 8 + i);
    *(float4*)&dst[t * NCOL + tx * 8]     = make_float4(acc[i][0], acc[i][1], acc[i][2], acc[i][3]);
    *(float4*)&dst[t * NCOL + tx * 8 + 4] = make_float4(acc[i][4], acc[i][5], acc[i][6], acc[i][7]);
  }
}

// ---------------- K2: combine partials + router epilogue ----------------
// grid = 1024 blocks x 1024 threads; one token per wave (16 waves/block)
__global__ __launch_bounds__(1024)
void epilogue_kernel(float* __restrict__ out) {
  const int tid  = threadIdx.x;
  const int lane = tid & 63;
  const int w    = tid >> 6;    // 0..15
  const int t    = blockIdx.x * 16 + w;

  float* out_rw  = out;                        // [16384][2]
  float* out_idx = out + 2 * TOKENS;           // [16384][2]
  float* out_rp  = out + 4 * TOKENS + 1;       // [16384][64]

  // combine split-K partials (independent loads -> latency hidden by occupancy)
  float cl = 0.0f, nl = 0.0f;
  #pragma unroll
  for (int s = 0; s < KSPLIT; ++s) {
    cl += g_part[s][t][lane];
    nl += g_part[s][t][NEXP + lane];
  }

  // router_probs = softmax(clean)
  const float m  = wave_max64(cl);
  const float v  = expf(cl - m);
  const float Z  = wave_sum64(v);
  const float rp = v / Z;
  out_rp[(size_t)t * NEXP + lane] = rp;

  // noisy logits
  const float ns  = softplus_ref(nl);
  const float noi = noise_normal((uint32_t)(t * NEXP + lane));
  const float lgn = __fadd_rn(cl, __fmul_rn(noi, ns));

  const float m2 = wave_max64(lgn);
  const float v2 = expf(lgn - m2);
  const float Z2 = wave_sum64(v2);
  const float p  = v2 / Z2;

  float p1; int i1;
  wave_argmax64(p, lane, p1, i1);
  const float pm = (lane == i1) ? -3.402823466e38f : p;
  float p2; int i2;
  wave_argmax64(pm, lane, p2, i2);

  const float c_acc = (float)((lane == i1) + (lane == i2));

  if (lane == 0) {
    const float s = p1 + p2;
    out_rw[t * 2 + 0]  = p1 / s;
    out_rw[t * 2 + 1]  = p2 / s;
    out_idx[t * 2 + 0] = (float)i1;
    out_idx[t * 2 + 1] = (float)i2;
  }

  // block-level reduce, then one atomicAdd set per block (1024 adds/address total)
  __shared__ float lps[16][NEXP];
  __shared__ float lcb[16][NEXP];
  __shared__ float lspw[16];
  lps[w][lane] = rp;
  lcb[w][lane] = c_acc;
  const float spw = wave_sum64(ns);
  if (lane == 0) lspw[w] = spw;
  __syncthreads();
  if (tid < NEXP) {
    float a = 0.0f, b = 0.0f;
    #pragma unroll
    for (int j = 0; j < 16; ++j) { a += lps[j][tid]; b += lcb[j][tid]; }
    atomicAdd(&g_ps[tid],  a);
    atomicAdd(&g_cnt[tid], b);
  }
  if (tid == 0) {
    float s = 0.0f;
    #pragma unroll
    for (int j = 0; j < 16; ++j) s += lspw[j];
    atomicAdd(&g_spa[0], s);
  }
}

// ---------------- K3: finalize scalars ----------------
__global__ void finalize_kernel(float* __restrict__ out) {
  const int lane = threadIdx.x;
  float term = (g_cnt[lane] / (float)TOKENS) * (g_ps[lane] / (float)TOKENS);
  #pragma unroll
  for (int off = 32; off; off >>= 1) term += __shfl_xor(term, off, 64);
  if (lane == 0) {
    out[4 * TOKENS] = 0.64f * term;   // LOAD_BALANCE_WEIGHT * NUM_EXPERTS
    out[4 * TOKENS + 1 + TOKENS * NEXP] = g_spa[0] / (float)(TOKENS * NEXP);
  }
}

// ---------------- host ----------------
extern "C" void kernel_launch(void* const* d_in, const int* in_sizes, int n_in,
                              void* d_out, int out_size, void* d_ws, size_t ws_size,
                              hipStream_t stream) {
  const float* x  = (const float*)d_in[0];   // f32 [4,4096,1024]
  const float* wg = (const float*)d_in[1];   // f32 [64,1024]
  const float* wn = (const float*)d_in[2];   // f32 [64,1024]
  float* out = (float*)d_out;                // f32, 1114114 elements

  (void)d_ws; (void)ws_size;

  NoisyTopKRouter_57621281243491_kernel<<<dim3(NTT, KSPLIT), 128, 0, stream>>>(x, wg, wn);
  epilogue_kernel<<<TOKENS / 16, 1024, 0, stream>>>(out);
  finalize_kernel<<<1, 64, 0, stream>>>(out);
}